// Round 1
// 466.995 us; speedup vs baseline: 1.0104x; 1.0104x over previous
//
#include <hip/hip_runtime.h>
#include <hip/hip_fp16.h>

// Fixed problem shape
#define TOK   64
#define INF   4096
#define OUTF  11008
#define NUMEL (OUTF * INF)        // 45088768
#define NSLC  (NUMEL / 64)        // 704512 64-element slices
#define NBLK  (OUTF / 16)         // 688 N-tiles
#define KSPL  4                   // GEMM K-split -> 2752 blocks

// Harness dtypes: fp16 arrays arrive as fp32; ints as int32; output fp32.
typedef __attribute__((ext_vector_type(8))) _Float16 half8;
typedef __attribute__((ext_vector_type(4))) _Float16 half4;
typedef __attribute__((ext_vector_type(4))) float floatx4;
typedef __attribute__((ext_vector_type(4), aligned(4))) int int4u;  // dword-aligned dwordx4

// ---------------------------------------------------------------------------
// Precompute: (a) x fp32 -> fp16 (512 KB, L2-resident GEMM A),
// (b) cum64[s] = lower_bound(fp16_pos, 64*s) for s = 0..NSLC — independent
// binary searches, latency fully overlapped.
// ---------------------------------------------------------------------------
__global__ __launch_bounds__(256) void precompute_kernel(
    const float* __restrict__ x, const int* __restrict__ fppos, int nf,
    _Float16* __restrict__ x16, int* __restrict__ cum64) {
  const int t = blockIdx.x * 256 + threadIdx.x;
  if (t < (TOK * INF) / 4) {
    const floatx4 f = *(const floatx4*)&x[t * 4];
    half4 h;
    h[0] = (_Float16)f[0]; h[1] = (_Float16)f[1];
    h[2] = (_Float16)f[2]; h[3] = (_Float16)f[3];
    *(half4*)&x16[t * 4] = h;
  }
  if (t <= NSLC) {
    const int target = t << 6;
    int lo = 0, hi = nf;
    while (lo < hi) {
      const int mid = (lo + hi) >> 1;
      if (fppos[mid] < target) lo = mid + 1; else hi = mid;
    }
    cum64[t] = lo;
  }
}

// ---------------------------------------------------------------------------
// Fused dequant of one positioned 8-slot [p0, p0+8) -> half8 B fragment.
// Verbatim logic from the verified standalone dequant kernel: compacted
// source start i0 = p0 - cum64 - lt; 2 predicated outlier probes of the
// 64-slice window (mean 0.177 outliers, P(>2)~1e-4 rare loop); i8 as two
// dword-aligned dwordx4; f!=0 repair consumes only the loaded 8 dwords.
// ---------------------------------------------------------------------------
__device__ __forceinline__ half8 dq_slot(
    const int p0, const float s,
    const int* __restrict__ i8, const float* __restrict__ fpdat,
    const int* __restrict__ fppos, const int* __restrict__ cum64,
    const int n8) {
  const int s64 = p0 >> 6;
  const int c0  = cum64[s64];
  const int c1  = cum64[s64 + 1];

  int lt = 0, f = 0;
  float ov[8];
#pragma unroll
  for (int e = 0; e < 8; ++e) ov[e] = 0.f;

  const int w = c1 - c0;
  if (w > 0) {  // ~16% of slices; short predicated body, no load loop
    {
      const int d = fppos[c0] - p0;
      const float v = fpdat[c0];
      lt += (d < 0);
      if ((unsigned)d < 8u) {
        f |= 1 << d;
#pragma unroll
        for (int e = 0; e < 8; ++e) ov[e] = (d == e) ? v : ov[e];
      }
    }
    if (w > 1) {
      const int d = fppos[c0 + 1] - p0;
      const float v = fpdat[c0 + 1];
      lt += (d < 0);
      if ((unsigned)d < 8u) {
        f |= 1 << d;
#pragma unroll
        for (int e = 0; e < 8; ++e) ov[e] = (d == e) ? v : ov[e];
      }
    }
    for (int j = 2; j < w; ++j) {  // P ~ 1e-4: correctness-only fallback
      const int d = fppos[c0 + j] - p0;
      const float v = fpdat[c0 + j];
      lt += (d < 0);
      if ((unsigned)d < 8u) {
        f |= 1 << d;
#pragma unroll
        for (int e = 0; e < 8; ++e) ov[e] = (d == e) ? v : ov[e];
      }
    }
  }

  const int i0 = p0 - c0 - lt;  // compacted index of position p0
  half8 oh;
  if (i0 + 8 <= n8) {
    int l[8];
    *(int4u*)&l[0] = *(const int4u*)&i8[i0];      // global_load_dwordx4
    *(int4u*)&l[4] = *(const int4u*)&i8[i0 + 4];  // (dword-aligned OK)
    if (f == 0) {
#pragma unroll
      for (int e = 0; e < 8; ++e) oh[e] = (_Float16)((float)l[e] * s);
    } else {
      // Repair: walk register file l[q], outlier slots take fp values.
      int q = 0;
#pragma unroll
      for (int e = 0; e < 8; ++e) {
        const int flg = (f >> e) & 1;
        int lv = l[0];
#pragma unroll
        for (int qq = 1; qq < 8; ++qq) lv = (q == qq) ? l[qq] : lv;
        oh[e] = flg ? (_Float16)ov[e] : (_Float16)((float)lv * s);
        q += 1 - flg;
      }
    }
  } else {
    // Array-tail path (last few slots of the flat array only): clamped loads.
    int c = 0;
    const int m = n8 - 1;
#pragma unroll
    for (int e = 0; e < 8; ++e) {
      const int flg = (f >> e) & 1;
      int idx = i0 + e - c;
      idx = idx < 0 ? 0 : (idx > m ? m : idx);
      oh[e] = flg ? (_Float16)ov[e] : (_Float16)((float)i8[idx] * s);
      c += flg;
    }
  }
  return oh;
}

// ---------------------------------------------------------------------------
// Fused GEMM: out = x @ dequant(W)^T + bias, B dequantized in-register —
// no materialized W (kills 90 MB write + 90 MB re-read + one dispatch).
// K-split grid (2752 blocks): block = (nt, kq) rows [nt*16,+16), K
// [kq*1024,+1024); wave = 256-K slice, 8 steps; full M=64 as 4 MFMA tiles.
// Per-thread quant scale is loop-invariant: the wave's 256-K slice sits
// inside one 1024 quant block -> s = scales[row*4 + kq].
// LDS cross-wave reduce + one atomicAdd per cell; kq==0 folds bias; out
// zeroed by hipMemsetAsync.
// mfma_f32_16x16x32_f16: A/B frag idx=lane&15, k=quad*8+j; D row=quad*4+i,
// col=lane&15  [verified in prior rounds].
// ---------------------------------------------------------------------------
__global__ __launch_bounds__(256) void gemm_fused(
    const _Float16* __restrict__ x16,
    const int* __restrict__ i8, const float* __restrict__ fpdat,
    const int* __restrict__ fppos, const float* __restrict__ scales,
    const int* __restrict__ cum64, const float* __restrict__ bias,
    float* __restrict__ out, const int n8) {
  __shared__ float red[4 * 64 * 16];  // 16 KB

  const int tid  = threadIdx.x;
  const int wave = tid >> 6;
  const int lane = tid & 63;
  const int quad = lane >> 4;
  const int ln   = lane & 15;
  const int nt   = blockIdx.x >> 2;
  const int kq   = blockIdx.x & 3;
  const int n0   = nt * 16;
  const int row  = n0 + ln;
  const int kb   = kq * 1024 + wave * 256 + quad * 8;
  const int pb   = row * INF + kb;          // flat position of this thread's B run
  const float s  = scales[row * 4 + kq];    // loop-invariant quant scale
  const _Float16* ap = &x16[ln * INF + kb];

  floatx4 acc0 = {0,0,0,0}, acc1 = {0,0,0,0}, acc2 = {0,0,0,0}, acc3 = {0,0,0,0};
#pragma unroll 4
  for (int st = 0; st < 8; ++st) {
    const int ko = st * 32;
    const half8 bh = dq_slot(pb + ko, s, i8, fpdat, fppos, cum64, n8);
    const half8 a0 = *(const half8*)&ap[ko];
    const half8 a1 = *(const half8*)&ap[16 * INF + ko];
    const half8 a2 = *(const half8*)&ap[32 * INF + ko];
    const half8 a3 = *(const half8*)&ap[48 * INF + ko];
    acc0 = __builtin_amdgcn_mfma_f32_16x16x32_f16(a0, bh, acc0, 0, 0, 0);
    acc1 = __builtin_amdgcn_mfma_f32_16x16x32_f16(a1, bh, acc1, 0, 0, 0);
    acc2 = __builtin_amdgcn_mfma_f32_16x16x32_f16(a2, bh, acc2, 0, 0, 0);
    acc3 = __builtin_amdgcn_mfma_f32_16x16x32_f16(a3, bh, acc3, 0, 0, 0);
  }

  const int mb = quad * 4;
#pragma unroll
  for (int i = 0; i < 4; ++i) red[wave * 1024 + (mb + i)      * 16 + ln] = acc0[i];
#pragma unroll
  for (int i = 0; i < 4; ++i) red[wave * 1024 + (16 + mb + i) * 16 + ln] = acc1[i];
#pragma unroll
  for (int i = 0; i < 4; ++i) red[wave * 1024 + (32 + mb + i) * 16 + ln] = acc2[i];
#pragma unroll
  for (int i = 0; i < 4; ++i) red[wave * 1024 + (48 + mb + i) * 16 + ln] = acc3[i];
  __syncthreads();

#pragma unroll
  for (int c2 = 0; c2 < 4; ++c2) {
    const int cell = tid + c2 * 256;  // 1024 cells = 64 m x 16 n
    const int mm = cell >> 4, nn = cell & 15;
    float v = red[cell] + red[1024 + cell] + red[2048 + cell] + red[3072 + cell];
    if (kq == 0) v += bias[n0 + nn];
    atomicAdd(&out[mm * OUTF + n0 + nn], v);
  }
}

// ---------------------------------------------------------------------------
// Inputs: 0 x(fp32) 1 int8_data(i32) 2 fp16_data(fp32) 3 scales(fp32)
// 4 bias(fp32) 5 int8_pos(UNUSED) 6 fp16_pos(i32) 7 block_idx(UNUSED)
// ws: x16 (512 KB) | cum64 (2.82 MB)   — W buffer eliminated (fused GEMM)
// ---------------------------------------------------------------------------
extern "C" void kernel_launch(void* const* d_in, const int* in_sizes, int n_in,
                              void* d_out, int out_size, void* d_ws,
                              size_t ws_size, hipStream_t stream) {
  const float* x      = (const float*)d_in[0];
  const int*   i8     = (const int*)d_in[1];
  const float* fpdat  = (const float*)d_in[2];
  const float* scales = (const float*)d_in[3];
  const float* bias   = (const float*)d_in[4];
  const int*   fppos  = (const int*)d_in[6];

  char* wsp = (char*)d_ws;
  _Float16* x16   = (_Float16*)wsp;
  int*      cum64 = (int*)(wsp + (size_t)TOK * INF * sizeof(_Float16));
  float*    out   = (float*)d_out;

  const int n8 = in_sizes[1];
  const int nf = in_sizes[2];

  hipMemsetAsync(out, 0, (size_t)out_size * sizeof(float), stream);
  precompute_kernel<<<(NSLC + 256) / 256 + 1, 256, 0, stream>>>(x, fppos, nf,
                                                                x16, cum64);
  gemm_fused<<<NBLK * KSPL, 256, 0, stream>>>(x16, i8, fpdat, fppos, scales,
                                              cum64, bias, out, n8);
}

// Round 2
// 452.331 us; speedup vs baseline: 1.0432x; 1.0324x over previous
//
#include <hip/hip_runtime.h>
#include <hip/hip_fp16.h>

// Fixed problem shape
#define TOK   64
#define INF   4096
#define OUTF  11008
#define NUMEL (OUTF * INF)        // 45088768
#define NSLC  (NUMEL / 64)        // 704512 64-element slices
#define NBLK  (OUTF / 16)         // 688 N-tiles
#define KSPL  8                   // GEMM K-split -> 5504 blocks, 512-K tiles

// Harness dtypes: fp16 arrays arrive as fp32; ints as int32; output fp32.
typedef __attribute__((ext_vector_type(8))) _Float16 half8;
typedef __attribute__((ext_vector_type(4))) _Float16 half4;
typedef __attribute__((ext_vector_type(4))) float floatx4;
typedef __attribute__((ext_vector_type(4), aligned(4))) int int4u;  // dword-aligned dwordx4

// LDS B-tile row padding: 512 + 8 fp16 -> row stride 1040 B.
// 1040 % 16 == 0 (ds_read_b128 stays 16B-aligned); dword stride 260 ->
// bank start 4*(ln+quad) mod 32: even 8-lane spread, no hot bank.
#define BPAD 520

// ---------------------------------------------------------------------------
// Precompute: (a) x fp32 -> fp16 (512 KB, L2-resident GEMM A),
// (b) cum64[s] = lower_bound(fp16_pos, 64*s) for s = 0..NSLC — independent
// binary searches, latency fully overlapped.
// ---------------------------------------------------------------------------
__global__ __launch_bounds__(256) void precompute_kernel(
    const float* __restrict__ x, const int* __restrict__ fppos, int nf,
    _Float16* __restrict__ x16, int* __restrict__ cum64) {
  const int t = blockIdx.x * 256 + threadIdx.x;
  if (t < (TOK * INF) / 4) {
    const floatx4 f = *(const floatx4*)&x[t * 4];
    half4 h;
    h[0] = (_Float16)f[0]; h[1] = (_Float16)f[1];
    h[2] = (_Float16)f[2]; h[3] = (_Float16)f[3];
    *(half4*)&x16[t * 4] = h;
  }
  if (t <= NSLC) {
    const int target = t << 6;
    int lo = 0, hi = nf;
    while (lo < hi) {
      const int mid = (lo + hi) >> 1;
      if (fppos[mid] < target) lo = mid + 1; else hi = mid;
    }
    cum64[t] = lo;
  }
}

// ---------------------------------------------------------------------------
// Dequant of one positioned 8-slot [p0, p0+8) -> half8. Verbatim verified
// logic: compacted source start i0 = p0 - cum64 - lt; 2 predicated outlier
// probes of the 64-slice window (mean 0.177 outliers, P(>2)~1e-4 rare loop);
// i8 as two dword-aligned dwordx4; f!=0 repair consumes only the 8 dwords.
// ---------------------------------------------------------------------------
__device__ __forceinline__ half8 dq_slot(
    const int p0, const float s,
    const int* __restrict__ i8, const float* __restrict__ fpdat,
    const int* __restrict__ fppos, const int* __restrict__ cum64,
    const int n8) {
  const int s64 = p0 >> 6;
  const int c0  = cum64[s64];
  const int c1  = cum64[s64 + 1];

  int lt = 0, f = 0;
  float ov[8];
#pragma unroll
  for (int e = 0; e < 8; ++e) ov[e] = 0.f;

  const int w = c1 - c0;
  if (w > 0) {  // ~16% of slices; short predicated body, no load loop
    {
      const int d = fppos[c0] - p0;
      const float v = fpdat[c0];
      lt += (d < 0);
      if ((unsigned)d < 8u) {
        f |= 1 << d;
#pragma unroll
        for (int e = 0; e < 8; ++e) ov[e] = (d == e) ? v : ov[e];
      }
    }
    if (w > 1) {
      const int d = fppos[c0 + 1] - p0;
      const float v = fpdat[c0 + 1];
      lt += (d < 0);
      if ((unsigned)d < 8u) {
        f |= 1 << d;
#pragma unroll
        for (int e = 0; e < 8; ++e) ov[e] = (d == e) ? v : ov[e];
      }
    }
    for (int j = 2; j < w; ++j) {  // P ~ 1e-4: correctness-only fallback
      const int d = fppos[c0 + j] - p0;
      const float v = fpdat[c0 + j];
      lt += (d < 0);
      if ((unsigned)d < 8u) {
        f |= 1 << d;
#pragma unroll
        for (int e = 0; e < 8; ++e) ov[e] = (d == e) ? v : ov[e];
      }
    }
  }

  const int i0 = p0 - c0 - lt;  // compacted index of position p0
  half8 oh;
  if (i0 + 8 <= n8) {
    int l[8];
    *(int4u*)&l[0] = *(const int4u*)&i8[i0];      // global_load_dwordx4
    *(int4u*)&l[4] = *(const int4u*)&i8[i0 + 4];  // (dword-aligned OK)
    if (f == 0) {
#pragma unroll
      for (int e = 0; e < 8; ++e) oh[e] = (_Float16)((float)l[e] * s);
    } else {
      // Repair: walk register file l[q], outlier slots take fp values.
      int q = 0;
#pragma unroll
      for (int e = 0; e < 8; ++e) {
        const int flg = (f >> e) & 1;
        int lv = l[0];
#pragma unroll
        for (int qq = 1; qq < 8; ++qq) lv = (q == qq) ? l[qq] : lv;
        oh[e] = flg ? (_Float16)ov[e] : (_Float16)((float)lv * s);
        q += 1 - flg;
      }
    }
  } else {
    // Array-tail path (last few slots of the flat array only): clamped loads.
    int c = 0;
    const int m = n8 - 1;
#pragma unroll
    for (int e = 0; e < 8; ++e) {
      const int flg = (f >> e) & 1;
      int idx = i0 + e - c;
      idx = idx < 0 ? 0 : (idx > m ? m : idx);
      oh[e] = flg ? (_Float16)ov[e] : (_Float16)((float)i8[idx] * s);
      c += flg;
    }
  }
  return oh;
}

// ---------------------------------------------------------------------------
// Fused GEMM v2: out = x @ dequant(W)^T + bias, with an LDS coalescing stage.
// R1 post-mortem: in-register fusion scattered the i8 loads (adjacent lanes =
// adjacent OUTPUT ROWS = 16 KB apart in the compacted stream) -> 64 txns per
// wave load, latency-bound at 1.1 TB/s / MfmaUtil 1.7%.
// v2: block (nt,kq) stages its positioned B-tile (16 rows x 512 K) into LDS
// with the LINEAR slot map (wave = one row's 64 consecutive 8-slots -> lanes
// read CONSECUTIVE i8, the proven standalone-dequant pattern), dequantized
// to fp16 with per-slot scale. MFMA phase then reads B fragments from LDS
// (padded rows: no hot bank). red[] aliases the B-tile (barrier-separated).
// Grid 5504 blocks; aliased LDS 16.6 KB -> up to 8 blocks/CU for staging TLP.
// mfma_f32_16x16x32_f16: A/B frag idx=lane&15, k=quad*8+j; D row=quad*4+i,
// col=lane&15  [verified in prior rounds].
// ---------------------------------------------------------------------------
__global__ __launch_bounds__(256) void gemm_fused(
    const _Float16* __restrict__ x16,
    const int* __restrict__ i8, const float* __restrict__ fpdat,
    const int* __restrict__ fppos, const float* __restrict__ scales,
    const int* __restrict__ cum64, const float* __restrict__ bias,
    float* __restrict__ out, const int n8) {
  __shared__ __attribute__((aligned(16))) char smem[16 * BPAD * 2];  // 16.6 KB
  _Float16 (* __restrict__ Bt)[BPAD] = (_Float16 (*)[BPAD])smem;
  float* red = (float*)smem;  // 16 KB, reused AFTER the MFMA phase

  const int tid  = threadIdx.x;
  const int wave = tid >> 6;
  const int lane = tid & 63;
  const int quad = lane >> 4;
  const int ln   = lane & 15;
  const int nt   = blockIdx.x >> 3;
  const int kq   = blockIdx.x & 7;
  const int n0   = nt * 16;
  const int kbas = kq * 512;

  // ---- Stage: dequant 16x512 positioned B-tile into LDS, coalesced ----
  // slot = i*256 + tid; row = slot>>6 (64 slots/row), k8 = slot&63.
  // A wave covers one row's 64 consecutive 8-slots -> i8 reads coalesced.
#pragma unroll 2
  for (int i = 0; i < 4; ++i) {
    const int slot = i * 256 + tid;
    const int r    = slot >> 6;
    const int k8   = slot & 63;
    const int p0   = (n0 + r) * INF + kbas + k8 * 8;
    const float s  = scales[p0 >> 10];
    const half8 oh = dq_slot(p0, s, i8, fpdat, fppos, cum64, n8);
    *(half8*)&Bt[r][k8 * 8] = oh;
  }
  __syncthreads();

  // ---- MFMA: wave = 128-K slice (4 steps), full M=64 as 4 tiles ----
  const int ko0 = wave * 128 + quad * 8;
  const _Float16* ap = &x16[ln * INF + kbas + ko0];
  const _Float16* bp = &Bt[ln][ko0];

  floatx4 acc0 = {0,0,0,0}, acc1 = {0,0,0,0}, acc2 = {0,0,0,0}, acc3 = {0,0,0,0};
#pragma unroll
  for (int st = 0; st < 4; ++st) {
    const int ko = st * 32;
    const half8 bh = *(const half8*)&bp[ko];          // ds_read_b128
    const half8 a0 = *(const half8*)&ap[ko];
    const half8 a1 = *(const half8*)&ap[16 * INF + ko];
    const half8 a2 = *(const half8*)&ap[32 * INF + ko];
    const half8 a3 = *(const half8*)&ap[48 * INF + ko];
    acc0 = __builtin_amdgcn_mfma_f32_16x16x32_f16(a0, bh, acc0, 0, 0, 0);
    acc1 = __builtin_amdgcn_mfma_f32_16x16x32_f16(a1, bh, acc1, 0, 0, 0);
    acc2 = __builtin_amdgcn_mfma_f32_16x16x32_f16(a2, bh, acc2, 0, 0, 0);
    acc3 = __builtin_amdgcn_mfma_f32_16x16x32_f16(a3, bh, acc3, 0, 0, 0);
  }
  __syncthreads();  // all B reads done before red[] overwrites the tile

  const int mb = quad * 4;
#pragma unroll
  for (int i = 0; i < 4; ++i) red[wave * 1024 + (mb + i)      * 16 + ln] = acc0[i];
#pragma unroll
  for (int i = 0; i < 4; ++i) red[wave * 1024 + (16 + mb + i) * 16 + ln] = acc1[i];
#pragma unroll
  for (int i = 0; i < 4; ++i) red[wave * 1024 + (32 + mb + i) * 16 + ln] = acc2[i];
#pragma unroll
  for (int i = 0; i < 4; ++i) red[wave * 1024 + (48 + mb + i) * 16 + ln] = acc3[i];
  __syncthreads();

#pragma unroll
  for (int c2 = 0; c2 < 4; ++c2) {
    const int cell = tid + c2 * 256;  // 1024 cells = 64 m x 16 n
    const int mm = cell >> 4, nn = cell & 15;
    float v = red[cell] + red[1024 + cell] + red[2048 + cell] + red[3072 + cell];
    if (kq == 0) v += bias[n0 + nn];
    atomicAdd(&out[mm * OUTF + n0 + nn], v);
  }
}

// ---------------------------------------------------------------------------
// Inputs: 0 x(fp32) 1 int8_data(i32) 2 fp16_data(fp32) 3 scales(fp32)
// 4 bias(fp32) 5 int8_pos(UNUSED) 6 fp16_pos(i32) 7 block_idx(UNUSED)
// ws: x16 (512 KB) | cum64 (2.82 MB)
// ---------------------------------------------------------------------------
extern "C" void kernel_launch(void* const* d_in, const int* in_sizes, int n_in,
                              void* d_out, int out_size, void* d_ws,
                              size_t ws_size, hipStream_t stream) {
  const float* x      = (const float*)d_in[0];
  const int*   i8     = (const int*)d_in[1];
  const float* fpdat  = (const float*)d_in[2];
  const float* scales = (const float*)d_in[3];
  const float* bias   = (const float*)d_in[4];
  const int*   fppos  = (const int*)d_in[6];

  char* wsp = (char*)d_ws;
  _Float16* x16   = (_Float16*)wsp;
  int*      cum64 = (int*)(wsp + (size_t)TOK * INF * sizeof(_Float16));
  float*    out   = (float*)d_out;

  const int n8 = in_sizes[1];
  const int nf = in_sizes[2];

  hipMemsetAsync(out, 0, (size_t)out_size * sizeof(float), stream);
  precompute_kernel<<<(NSLC + 256) / 256 + 1, 256, 0, stream>>>(x, fppos, nf,
                                                                x16, cum64);
  gemm_fused<<<NBLK * KSPL, 256, 0, stream>>>(x16, i8, fpdat, fppos, scales,
                                              cum64, bias, out, n8);
}

// Round 3
// 446.024 us; speedup vs baseline: 1.0579x; 1.0141x over previous
//
#include <hip/hip_runtime.h>
#include <hip/hip_fp16.h>

// Fixed problem shape
#define TOK   64
#define INF   4096
#define OUTF  11008
#define NUMEL (OUTF * INF)        // 45088768
#define NSLC  (NUMEL / 64)        // 704512 64-element slices
#define NBLK  (OUTF / 16)         // 688 N-tiles
#define KSPL  8                   // GEMM K-split -> 5504 blocks, 512-K tiles
#define OUTN  (TOK * OUTF)        // 704512 output elems

// Harness dtypes: fp16 arrays arrive as fp32; ints as int32; output fp32.
typedef __attribute__((ext_vector_type(8))) _Float16 half8;
typedef __attribute__((ext_vector_type(4))) _Float16 half4;
typedef __attribute__((ext_vector_type(4))) float floatx4;
typedef __attribute__((ext_vector_type(4), aligned(4))) int int4u;   // dword-aligned dwordx4
typedef __attribute__((ext_vector_type(4))) int int4a;               // 16B-aligned dwordx4

// LDS B-tile row padding: 512 + 8 fp16 -> row stride 1040 B (16B-aligned,
// dword stride 260 -> even bank spread).
#define BPAD 520

// ---------------------------------------------------------------------------
// Precompute: (a) x fp32 -> fp16 (512 KB, L2-resident GEMM A),
// (b) per-64-slice meta[s] = {c0 = lower_bound(fp16_pos, 64*s),
//     outlier mask (bit d => position 64s+d is an fp16 outlier), pad}.
// One 16 B record; the GEMM's i8 address then depends on ONE load.
// Mask scan is mean 0.17 iterations (outlier density 2.7e-3 * 64).
// ---------------------------------------------------------------------------
__global__ __launch_bounds__(256) void precompute_kernel(
    const float* __restrict__ x, const int* __restrict__ fppos, int nf,
    _Float16* __restrict__ x16, int* __restrict__ meta) {
  const int t = blockIdx.x * 256 + threadIdx.x;
  if (t < (TOK * INF) / 4) {
    const floatx4 f = *(const floatx4*)&x[t * 4];
    half4 h;
    h[0] = (_Float16)f[0]; h[1] = (_Float16)f[1];
    h[2] = (_Float16)f[2]; h[3] = (_Float16)f[3];
    *(half4*)&x16[t * 4] = h;
  }
  if (t < NSLC) {
    const int target = t << 6;
    int lo = 0, hi = nf;
    while (lo < hi) {
      const int mid = (lo + hi) >> 1;
      if (fppos[mid] < target) lo = mid + 1; else hi = mid;
    }
    unsigned long long mask = 0ull;
    int j = lo;
    while (j < nf) {                 // mean 0.17 iters; P(>2) ~ 1e-4
      const int d = fppos[j] - target;
      if (d >= 64) break;
      mask |= 1ull << d;
      ++j;
    }
    int4a mv;
    mv[0] = lo;
    mv[1] = (int)(unsigned)(mask & 0xffffffffu);
    mv[2] = (int)(unsigned)(mask >> 32);
    mv[3] = 0;
    *(int4a*)&meta[t * 4] = mv;
  }
}

// ---------------------------------------------------------------------------
// Dequant of one positioned 8-slot [p0, p0+8) -> half8, meta-driven.
// i0 = p0 - c0 - popc(mask below off): address ready after the single meta
// load (no fppos probe on the critical path). Outlier values load directly
// as fpdat[c0 + lt + rank] (rank from m8 bits), off the address path.
// i8 as two dword-aligned dwordx4; repair consumes only the 8 loaded dwords.
// ---------------------------------------------------------------------------
__device__ __forceinline__ half8 dq_slot_meta(
    const int p0, const int c0, const unsigned mlo, const unsigned mhi,
    const float s, const int* __restrict__ i8,
    const float* __restrict__ fpdat, const int n8) {
  const int off = p0 & 63;  // multiple of 8; 8-bit window never straddles
  const unsigned m8 = 0xffu & (off < 32 ? (mlo >> off) : (mhi >> (off - 32)));
  const unsigned bl = (off >= 32) ? mlo : (mlo & ((1u << off) - 1u));
  const unsigned bh = (off >= 32) ? (mhi & ((1u << (off - 32)) - 1u)) : 0u;
  const int lt = __popc(bl) + __popc(bh);
  const int i0 = p0 - c0 - lt;  // compacted index of position p0
  const int f  = (int)m8;

  float ov[8];
#pragma unroll
  for (int e = 0; e < 8; ++e) ov[e] = 0.f;
  if (f) {
    int fi = c0 + lt;
#pragma unroll
    for (int e = 0; e < 8; ++e) {
      if ((f >> e) & 1) { ov[e] = fpdat[fi]; ++fi; }
    }
  }

  half8 oh;
  if (i0 + 8 <= n8) {
    int l[8];
    *(int4u*)&l[0] = *(const int4u*)&i8[i0];      // global_load_dwordx4
    *(int4u*)&l[4] = *(const int4u*)&i8[i0 + 4];  // (dword-aligned OK)
    if (f == 0) {
#pragma unroll
      for (int e = 0; e < 8; ++e) oh[e] = (_Float16)((float)l[e] * s);
    } else {
      // Repair: walk register file l[q], outlier slots take fp values.
      int q = 0;
#pragma unroll
      for (int e = 0; e < 8; ++e) {
        const int flg = (f >> e) & 1;
        int lv = l[0];
#pragma unroll
        for (int qq = 1; qq < 8; ++qq) lv = (q == qq) ? l[qq] : lv;
        oh[e] = flg ? (_Float16)ov[e] : (_Float16)((float)lv * s);
        q += 1 - flg;
      }
    }
  } else {
    // Array-tail path (last few global slots only): clamped scalar loads.
    int c = 0;
    const int m = n8 - 1;
#pragma unroll
    for (int e = 0; e < 8; ++e) {
      const int flg = (f >> e) & 1;
      int idx = i0 + e - c;
      idx = idx < 0 ? 0 : (idx > m ? m : idx);
      oh[e] = flg ? (_Float16)ov[e] : (_Float16)((float)i8[idx] * s);
      c += flg;
    }
  }
  return oh;
}

// ---------------------------------------------------------------------------
// Fused GEMM v3: LDS-staged dequant (coalesced, R2) + meta-driven addressing
// (chain depth 3 -> 2, R3) + batched phase-1 meta loads (all 4 slots' meta
// and scale in flight together) + plain partial stores (atomics removed).
// Block (nt,kq): rows [nt*16,+16), K [kq*512,+512). Stage wave = one row's
// 64 consecutive 8-slots -> i8 reads coalesced (2 KB/wave). MFMA phase reads
// B from LDS; red[] aliases the tile (barrier-separated). Partials to
// part[kq] (22.5 MB streamed), summed by reduce_kernel.
// mfma_f32_16x16x32_f16: A/B frag idx=lane&15, k=quad*8+j; D row=quad*4+i,
// col=lane&15  [verified in prior rounds].
// ---------------------------------------------------------------------------
__global__ __launch_bounds__(256) void gemm_fused(
    const _Float16* __restrict__ x16,
    const int* __restrict__ i8, const float* __restrict__ fpdat,
    const float* __restrict__ scales, const int* __restrict__ meta,
    float* __restrict__ part, const int n8) {
  __shared__ __attribute__((aligned(16))) char smem[16 * BPAD * 2];  // 16.6 KB
  _Float16 (* __restrict__ Bt)[BPAD] = (_Float16 (*)[BPAD])smem;
  float* red = (float*)smem;  // 16 KB, reused AFTER the MFMA phase

  const int tid  = threadIdx.x;
  const int wave = tid >> 6;
  const int lane = tid & 63;
  const int quad = lane >> 4;
  const int ln   = lane & 15;
  const int nt   = blockIdx.x >> 3;
  const int kq   = blockIdx.x & 7;
  const int n0   = nt * 16;
  const int kbas = kq * 512;

  // ---- Phase 1: batched meta + scale loads (all independent, in flight) ----
  int p0v[4], c0v[4];
  unsigned mlov[4], mhiv[4];
  float sv[4];
#pragma unroll
  for (int i = 0; i < 4; ++i) {
    const int slot = i * 256 + tid;
    const int r    = slot >> 6;
    const int k8   = slot & 63;
    const int p0   = (n0 + r) * INF + kbas + k8 * 8;
    const int4a mv = *(const int4a*)&meta[(p0 >> 6) * 4];
    p0v[i] = p0;
    c0v[i] = mv[0];
    mlov[i] = (unsigned)mv[1];
    mhiv[i] = (unsigned)mv[2];
    sv[i]  = scales[p0 >> 10];
  }

  // ---- Phase 2: dequant + LDS write (i8 addresses all ready -> compiler
  // can hoist the 8 dwordx4 ahead of the converts) ----
#pragma unroll
  for (int i = 0; i < 4; ++i) {
    const int slot = i * 256 + tid;
    const int r    = slot >> 6;
    const int k8   = slot & 63;
    const half8 oh = dq_slot_meta(p0v[i], c0v[i], mlov[i], mhiv[i], sv[i],
                                  i8, fpdat, n8);
    *(half8*)&Bt[r][k8 * 8] = oh;
  }
  __syncthreads();

  // ---- MFMA: wave = 128-K slice (4 steps), full M=64 as 4 tiles ----
  const int ko0 = wave * 128 + quad * 8;
  const _Float16* ap = &x16[ln * INF + kbas + ko0];
  const _Float16* bp = &Bt[ln][ko0];

  floatx4 acc0 = {0,0,0,0}, acc1 = {0,0,0,0}, acc2 = {0,0,0,0}, acc3 = {0,0,0,0};
#pragma unroll
  for (int st = 0; st < 4; ++st) {
    const int ko = st * 32;
    const half8 bh = *(const half8*)&bp[ko];          // ds_read_b128
    const half8 a0 = *(const half8*)&ap[ko];
    const half8 a1 = *(const half8*)&ap[16 * INF + ko];
    const half8 a2 = *(const half8*)&ap[32 * INF + ko];
    const half8 a3 = *(const half8*)&ap[48 * INF + ko];
    acc0 = __builtin_amdgcn_mfma_f32_16x16x32_f16(a0, bh, acc0, 0, 0, 0);
    acc1 = __builtin_amdgcn_mfma_f32_16x16x32_f16(a1, bh, acc1, 0, 0, 0);
    acc2 = __builtin_amdgcn_mfma_f32_16x16x32_f16(a2, bh, acc2, 0, 0, 0);
    acc3 = __builtin_amdgcn_mfma_f32_16x16x32_f16(a3, bh, acc3, 0, 0, 0);
  }
  __syncthreads();  // all B reads done before red[] overwrites the tile

  const int mb = quad * 4;
#pragma unroll
  for (int i = 0; i < 4; ++i) red[wave * 1024 + (mb + i)      * 16 + ln] = acc0[i];
#pragma unroll
  for (int i = 0; i < 4; ++i) red[wave * 1024 + (16 + mb + i) * 16 + ln] = acc1[i];
#pragma unroll
  for (int i = 0; i < 4; ++i) red[wave * 1024 + (32 + mb + i) * 16 + ln] = acc2[i];
#pragma unroll
  for (int i = 0; i < 4; ++i) red[wave * 1024 + (48 + mb + i) * 16 + ln] = acc3[i];
  __syncthreads();

  // ---- Plain partial store (no atomics, no memset dependency) ----
  float* pp = &part[(size_t)kq * OUTN];
#pragma unroll
  for (int c2 = 0; c2 < 4; ++c2) {
    const int cell = tid + c2 * 256;  // 1024 cells = 64 m x 16 n
    const int mm = cell >> 4, nn = cell & 15;
    pp[mm * OUTF + n0 + nn] =
        red[cell] + red[1024 + cell] + red[2048 + cell] + red[3072 + cell];
  }
}

// ---------------------------------------------------------------------------
// Reduce: out = sum_kq part[kq] + bias. 176128 threads x float4.
// 22.5 MB read + 2.8 MB write ~ 4-5 us at BW.
// ---------------------------------------------------------------------------
__global__ __launch_bounds__(256) void reduce_kernel(
    const float* __restrict__ part, const float* __restrict__ bias,
    float* __restrict__ out) {
  const int t  = blockIdx.x * 256 + threadIdx.x;  // 688*256 = 176128 exact
  const int i4 = t * 4;
  floatx4 a = *(const floatx4*)&part[i4];
#pragma unroll
  for (int k = 1; k < KSPL; ++k) {
    const floatx4 b = *(const floatx4*)&part[(size_t)k * OUTN + i4];
    a[0] += b[0]; a[1] += b[1]; a[2] += b[2]; a[3] += b[3];
  }
  const int nn = i4 % OUTF;  // OUTF % 4 == 0: float4 never straddles rows
  const floatx4 bb = *(const floatx4*)&bias[nn];
  a[0] += bb[0]; a[1] += bb[1]; a[2] += bb[2]; a[3] += bb[3];
  *(floatx4*)&out[i4] = a;
}

// ---------------------------------------------------------------------------
// Inputs: 0 x(fp32) 1 int8_data(i32) 2 fp16_data(fp32) 3 scales(fp32)
// 4 bias(fp32) 5 int8_pos(UNUSED) 6 fp16_pos(i32) 7 block_idx(UNUSED)
// ws: x16 (512 KB) | meta (11.3 MB) | part (22.5 MB)
// ---------------------------------------------------------------------------
extern "C" void kernel_launch(void* const* d_in, const int* in_sizes, int n_in,
                              void* d_out, int out_size, void* d_ws,
                              size_t ws_size, hipStream_t stream) {
  const float* x      = (const float*)d_in[0];
  const int*   i8     = (const int*)d_in[1];
  const float* fpdat  = (const float*)d_in[2];
  const float* scales = (const float*)d_in[3];
  const float* bias   = (const float*)d_in[4];
  const int*   fppos  = (const int*)d_in[6];

  char* wsp = (char*)d_ws;
  _Float16* x16  = (_Float16*)wsp;
  int*      meta = (int*)(wsp + (size_t)TOK * INF * sizeof(_Float16));
  float*    part = (float*)(wsp + (size_t)TOK * INF * sizeof(_Float16)
                                + (size_t)NSLC * 16);
  float*    out  = (float*)d_out;

  const int n8 = in_sizes[1];
  const int nf = in_sizes[2];

  precompute_kernel<<<NSLC / 256, 256, 0, stream>>>(x, fppos, nf, x16, meta);
  gemm_fused<<<NBLK * KSPL, 256, 0, stream>>>(x16, i8, fpdat, scales, meta,
                                              part, n8);
  reduce_kernel<<<OUTN / (4 * 256), 256, 0, stream>>>(part, bias, out);
}